// Round 1
// baseline (372.664 us; speedup 1.0000x reference)
//
#include <hip/hip_runtime.h>
#include <stdint.h>

// ---------------------------------------------------------------------------
// CrossMultiheadDiffAttn on MI355X (gfx950)
// B=2, T=S=2048, EMBED=1024, HEADS=16, HEAD_DIM=32 (2H=32 qk-heads of 32,
// 16 v-heads of 64).
//
// Pipeline (all f16 operands, f32 accumulation):
//   1. cvt: query_x, kv_x f32 -> f16
//   2. wtrans: Wq*scale, Wk, Wv, Wo f32 [K,N] -> f16 [N,K] (transposed)
//   3. lambda_k: lambda_full = exp(sum lq1*lk1) - exp(sum lq2*lk2) + LAMBDA_INIT
//   4. gemm128: q = xq@WqT, k = xkv@WkT, v = xkv@WvT   (f16 out)
//   5. diffattn: flash-style dual online-softmax diff attention + RMSNorm
//   6. gemm128: out = attn16 @ WoT (f32 out)
//
// Workspace layout (f16 elems unless noted), total ~56 MiB:
//   xq[4M] xkv[4M] WqT[1M] WkT[1M] WvT[1M] WoT[1M] qb[4M] kb[4M] vb[4M]
//   attn16[4M] lambda(1 float)
// ---------------------------------------------------------------------------

#define T_LEN 2048
#define EMBED 1024
#define HD 32
#define LAMBDA_INIT_F 0.7836057665316245f
#define OUT_SCALE_F   0.2163942334683755f   /* 1 - LAMBDA_INIT */
#define QK_SCALE_F    0.17677669529663687f  /* 32^-0.5 */

typedef _Float16 f16x8 __attribute__((ext_vector_type(8)));
typedef _Float16 f16x4 __attribute__((ext_vector_type(4)));
typedef float    f32x4 __attribute__((ext_vector_type(4)));

__device__ inline void gl_lds16(const void* g, void* l) {
  __builtin_amdgcn_global_load_lds(
      (const __attribute__((address_space(1))) void*)g,
      (__attribute__((address_space(3))) void*)l, 16, 0, 0);
}

// --------------------------- f32 -> f16 convert ----------------------------
__global__ __launch_bounds__(256) void cvt_kernel(const float* __restrict__ x,
                                                  _Float16* __restrict__ y) {
  int i = (blockIdx.x * 256 + threadIdx.x) * 4;
  float4 v = *(const float4*)(x + i);
  f16x4 o;
  o[0] = (_Float16)v.x; o[1] = (_Float16)v.y;
  o[2] = (_Float16)v.z; o[3] = (_Float16)v.w;
  *(f16x4*)(y + i) = o;
}

// ---------------- W [K,N] f32 -> W^T [N,K] f16 (with scale) ----------------
__global__ __launch_bounds__(256) void wtrans_kernel(const float* __restrict__ W,
                                                     _Float16* __restrict__ Wt,
                                                     float scale) {
  __shared__ _Float16 t[64][65];
  const int tid = threadIdx.x;
  const int nb = blockIdx.x * 64, kb = blockIdx.y * 64;
#pragma unroll
  for (int p = 0; p < 16; ++p) {
    int i = p * 256 + tid;
    int r = i >> 6, c = i & 63;  // r = k-local, c = n-local
    t[c][r] = (_Float16)(W[(size_t)(kb + r) * 1024 + nb + c] * scale);
  }
  __syncthreads();
#pragma unroll
  for (int p = 0; p < 16; ++p) {
    int i = p * 256 + tid;
    int r = i >> 6, c = i & 63;  // r = n-local, c = k-local
    Wt[(size_t)(nb + r) * 1024 + kb + c] = t[r][c];
  }
}

// ------------------------------ lambda_full --------------------------------
__global__ void lambda_kernel(const float* __restrict__ lq1, const float* __restrict__ lk1,
                              const float* __restrict__ lq2, const float* __restrict__ lk2,
                              float* __restrict__ out) {
  int l = threadIdx.x;  // 64 threads
  float a = (l < 32) ? lq1[l] * lk1[l] : 0.f;
  float b = (l < 32) ? lq2[l] * lk2[l] : 0.f;
#pragma unroll
  for (int m = 1; m < 64; m <<= 1) {
    a += __shfl_xor(a, m, 64);
    b += __shfl_xor(b, m, 64);
  }
  if (l == 0) out[0] = expf(a) - expf(b) + LAMBDA_INIT_F;
}

// --------------------- 128x128 f16 GEMM:  C = A @ Bt^T ---------------------
// A [M,K] row-major f16, Bt [N,K] row-major f16 (i.e. B transposed).
// grid = (N/128, M/128), 256 threads (4 waves, each a 64x64 quadrant).
__global__ __launch_bounds__(256) void gemm128(const _Float16* __restrict__ A,
                                               const _Float16* __restrict__ Bt,
                                               _Float16* __restrict__ Cf16,
                                               float* __restrict__ Cf32,
                                               int M, int N, int K) {
  __shared__ alignas(16) _Float16 As[128 * 32];
  __shared__ alignas(16) _Float16 Bs[128 * 32];
  const int tid = threadIdx.x;
  const int lane = tid & 63, wid = tid >> 6;
  const int g = lane >> 4, ln = lane & 15;
  const int wm = wid >> 1, wn = wid & 1;
  const int bm = blockIdx.y * 128;
  const int bn = blockIdx.x * 128;

  f32x4 acc[4][4];
#pragma unroll
  for (int i = 0; i < 4; ++i)
#pragma unroll
    for (int j = 0; j < 4; ++j) acc[i][j] = (f32x4){0.f, 0.f, 0.f, 0.f};

  const int r0 = tid >> 2;         // 0..63
  const int c0 = (tid & 3) * 8;    // 0,8,16,24

  for (int kt = 0; kt < K; kt += 32) {
    __syncthreads();
#pragma unroll
    for (int l = 0; l < 2; ++l) {
      const _Float16* ga = A + (size_t)(bm + l * 64 + r0) * K + kt + c0;
      const _Float16* gb = Bt + (size_t)(bn + l * 64 + r0) * K + kt + c0;
      // LDS dest: wave-uniform base; HW scatters lane*16B -> linear row-major tile
      gl_lds16(ga, (void*)(As + l * 2048 + wid * 512));
      gl_lds16(gb, (void*)(Bs + l * 2048 + wid * 512));
    }
    __syncthreads();
    f16x8 af[4], bf[4];
#pragma unroll
    for (int i = 0; i < 4; ++i) {
      af[i] = *(const f16x8*)(As + (wm * 64 + i * 16 + ln) * 32 + g * 8);
      bf[i] = *(const f16x8*)(Bs + (wn * 64 + i * 16 + ln) * 32 + g * 8);
    }
#pragma unroll
    for (int i = 0; i < 4; ++i)
#pragma unroll
      for (int j = 0; j < 4; ++j)
        acc[i][j] = __builtin_amdgcn_mfma_f32_16x16x32_f16(af[i], bf[j], acc[i][j], 0, 0, 0);
  }

#pragma unroll
  for (int i = 0; i < 4; ++i) {
#pragma unroll
    for (int j = 0; j < 4; ++j) {
      int grow = bm + wm * 64 + i * 16 + g * 4;
      int gcol = bn + wn * 64 + j * 16 + ln;
#pragma unroll
      for (int r = 0; r < 4; ++r) {
        if (Cf32) Cf32[(size_t)(grow + r) * N + gcol] = acc[i][j][r];
        else      Cf16[(size_t)(grow + r) * N + gcol] = (_Float16)acc[i][j][r];
      }
    }
  }
}

// ------------------- flash-style differential attention --------------------
// grid = B*H*(T/64) = 1024 blocks, 256 threads (4 waves x 16 q-rows).
// qb/kb: [B*T, 1024] f16, col = hq*32+d (hq in [0,32)). vb: col = h*64+e.
// Per s-tile (64): stage K(2 heads) + V^T in LDS; per wave: QK^T MFMA,
// online softmax (state per D-frag row 4g+j), P->LDS->A-frag, PV MFMA x2 comp.
__global__ __launch_bounds__(256) void diffattn(const _Float16* __restrict__ qb,
                                                const _Float16* __restrict__ kb,
                                                const _Float16* __restrict__ vb,
                                                const float* __restrict__ lam_p,
                                                const float* __restrict__ subw,
                                                _Float16* __restrict__ attn16) {
  __shared__ alignas(16) _Float16 K1s[64][40];
  __shared__ alignas(16) _Float16 K2s[64][40];
  __shared__ alignas(16) _Float16 Vts[64][72];   // Vts[e][s] = V[s][e]
  __shared__ alignas(16) _Float16 P1s[4][16][72];
  __shared__ alignas(16) _Float16 P2s[4][16][72];

  const int tid = threadIdx.x;
  const int lane = tid & 63, wid = tid >> 6;
  const int g = lane >> 4, ln = lane & 15;
  const int bid = blockIdx.x;
  const int qt = bid & 31;
  const int h = (bid >> 5) & 15;
  const int b = bid >> 9;
  const int t0 = qt * 64;
  const float lam = lam_p[0];

  const size_t qrow = ((size_t)b * T_LEN + t0 + wid * 16 + ln) * EMBED;
  f16x8 q1 = *(const f16x8*)(qb + qrow + (2 * h) * HD + g * 8);
  f16x8 q2 = *(const f16x8*)(qb + qrow + (2 * h + 1) * HD + g * 8);

  float m1[4], l1[4], m2[4], l2[4];
  f32x4 O1[4], O2[4];
#pragma unroll
  for (int j = 0; j < 4; ++j) { m1[j] = m2[j] = -1e30f; l1[j] = l2[j] = 0.f; }
#pragma unroll
  for (int e = 0; e < 4; ++e) { O1[e] = (f32x4){0,0,0,0}; O2[e] = (f32x4){0,0,0,0}; }

  const int kr = tid >> 2, kc = (tid & 3) * 8;

  for (int s0 = 0; s0 < T_LEN; s0 += 64) {
    __syncthreads();
    {  // stage K1, K2 (64x32 each) and V^T (64x64)
      const _Float16* kp = kb + ((size_t)b * T_LEN + s0 + kr) * EMBED + 2 * h * HD;
      *(f16x8*)&K1s[kr][kc] = *(const f16x8*)(kp + kc);
      *(f16x8*)&K2s[kr][kc] = *(const f16x8*)(kp + HD + kc);
#pragma unroll
      for (int q = 0; q < 2; ++q) {
        int idx = tid * 2 + q;
        int s = idx >> 3, c8 = (idx & 7) * 8;
        f16x8 vv = *(const f16x8*)(vb + ((size_t)b * T_LEN + s0 + s) * EMBED + h * 64 + c8);
#pragma unroll
        for (int i = 0; i < 8; ++i) Vts[c8 + i][s] = vv[i];
      }
    }
    __syncthreads();

    // QK^T scores for both components
    f32x4 sc[2][4];
#pragma unroll
    for (int c = 0; c < 2; ++c) {
      f16x8 qf = c ? q2 : q1;
      _Float16(*Ks)[40] = c ? K2s : K1s;
#pragma unroll
      for (int kcc = 0; kcc < 4; ++kcc) {
        f16x8 kf = *(const f16x8*)&Ks[kcc * 16 + ln][g * 8];
        sc[c][kcc] = __builtin_amdgcn_mfma_f32_16x16x32_f16(qf, kf, (f32x4){0,0,0,0}, 0, 0, 0);
      }
    }

    // online softmax per component; P (f16) -> per-wave LDS tile
#pragma unroll
    for (int c = 0; c < 2; ++c) {
      float* m = c ? m2 : m1;
      float* l = c ? l2 : l1;
      f32x4* O = c ? O2 : O1;
      _Float16(*Ps)[72] = c ? P2s[wid] : P1s[wid];
      float tm[4], rs[4], corr[4];
#pragma unroll
      for (int j = 0; j < 4; ++j)
        tm[j] = fmaxf(fmaxf(sc[c][0][j], sc[c][1][j]), fmaxf(sc[c][2][j], sc[c][3][j]));
#pragma unroll
      for (int msk = 1; msk < 16; msk <<= 1)
#pragma unroll
        for (int j = 0; j < 4; ++j) tm[j] = fmaxf(tm[j], __shfl_xor(tm[j], msk, 64));
#pragma unroll
      for (int j = 0; j < 4; ++j) {
        float mn = fmaxf(m[j], tm[j]);
        corr[j] = __expf(m[j] - mn);
        m[j] = mn;
        float rsum = 0.f;
#pragma unroll
        for (int kcc = 0; kcc < 4; ++kcc) {
          float p = __expf(sc[c][kcc][j] - mn);
          Ps[g * 4 + j][kcc * 16 + ln] = (_Float16)p;
          rsum += p;
        }
        rs[j] = rsum;
      }
#pragma unroll
      for (int msk = 1; msk < 16; msk <<= 1)
#pragma unroll
        for (int j = 0; j < 4; ++j) rs[j] += __shfl_xor(rs[j], msk, 64);
#pragma unroll
      for (int j = 0; j < 4; ++j) l[j] = l[j] * corr[j] + rs[j];
#pragma unroll
      for (int e = 0; e < 4; ++e)
#pragma unroll
        for (int j = 0; j < 4; ++j) O[e][j] *= corr[j];
    }

    // PV: O_c += P_c @ V  (V-frag loaded once, used by both components)
#pragma unroll
    for (int ss = 0; ss < 2; ++ss) {
      f16x8 p1 = *(const f16x8*)&P1s[wid][ln][ss * 32 + g * 8];
      f16x8 p2 = *(const f16x8*)&P2s[wid][ln][ss * 32 + g * 8];
#pragma unroll
      for (int e = 0; e < 4; ++e) {
        f16x8 vf = *(const f16x8*)&Vts[e * 16 + ln][ss * 32 + g * 8];
        O1[e] = __builtin_amdgcn_mfma_f32_16x16x32_f16(p1, vf, O1[e], 0, 0, 0);
        O2[e] = __builtin_amdgcn_mfma_f32_16x16x32_f16(p2, vf, O2[e], 0, 0, 0);
      }
    }
  }

  // epilogue: diff, RMSNorm over 64 dims, scale, store f16
  float x[4][4];
  float ssq[4] = {0.f, 0.f, 0.f, 0.f};
#pragma unroll
  for (int e = 0; e < 4; ++e)
#pragma unroll
    for (int j = 0; j < 4; ++j) {
      float v = O1[e][j] / l1[j] - lam * (O2[e][j] / l2[j]);
      x[e][j] = v;
      ssq[j] += v * v;
    }
#pragma unroll
  for (int msk = 1; msk < 16; msk <<= 1)
#pragma unroll
    for (int j = 0; j < 4; ++j) ssq[j] += __shfl_xor(ssq[j], msk, 64);
  float w[4];
#pragma unroll
  for (int e = 0; e < 4; ++e) w[e] = subw[e * 16 + ln];
#pragma unroll
  for (int j = 0; j < 4; ++j) {
    float rms = rsqrtf(ssq[j] * (1.f / 64.f) + 1e-5f) * OUT_SCALE_F;
    size_t row = ((size_t)b * T_LEN + t0 + wid * 16 + g * 4 + j) * EMBED + h * 64;
#pragma unroll
    for (int e = 0; e < 4; ++e)
      attn16[row + e * 16 + ln] = (_Float16)(x[e][j] * rms * w[e]);
  }
}

// ---------------------------------------------------------------------------
extern "C" void kernel_launch(void* const* d_in, const int* in_sizes, int n_in,
                              void* d_out, int out_size, void* d_ws, size_t ws_size,
                              hipStream_t stream) {
  const float* query_x = (const float*)d_in[0];
  const float* kv_x    = (const float*)d_in[1];
  const float* Wq      = (const float*)d_in[2];
  const float* Wk      = (const float*)d_in[3];
  const float* Wv      = (const float*)d_in[4];
  const float* Wo      = (const float*)d_in[5];
  const float* lq1     = (const float*)d_in[6];
  const float* lk1     = (const float*)d_in[7];
  const float* lq2     = (const float*)d_in[8];
  const float* lk2     = (const float*)d_in[9];
  const float* subw    = (const float*)d_in[10];
  float* out = (float*)d_out;

  const size_t NX = (size_t)4096 * 1024;  // 4M elems
  const size_t NW = (size_t)1024 * 1024;  // 1M elems
  _Float16* xq  = (_Float16*)d_ws;
  _Float16* xkv = xq  + NX;
  _Float16* WqT = xkv + NX;
  _Float16* WkT = WqT + NW;
  _Float16* WvT = WkT + NW;
  _Float16* WoT = WvT + NW;
  _Float16* qb  = WoT + NW;
  _Float16* kbf = qb  + NX;
  _Float16* vbf = kbf + NX;
  _Float16* a16 = vbf + NX;
  float* lamv   = (float*)(a16 + NX);   // total ~56 MiB + 4B

  cvt_kernel<<<4096, 256, 0, stream>>>(query_x, xq);
  cvt_kernel<<<4096, 256, 0, stream>>>(kv_x, xkv);

  dim3 tg(16, 16);
  wtrans_kernel<<<tg, 256, 0, stream>>>(Wq, WqT, QK_SCALE_F);
  wtrans_kernel<<<tg, 256, 0, stream>>>(Wk, WkT, 1.0f);
  wtrans_kernel<<<tg, 256, 0, stream>>>(Wv, WvT, 1.0f);
  wtrans_kernel<<<tg, 256, 0, stream>>>(Wo, WoT, 1.0f);
  lambda_kernel<<<1, 64, 0, stream>>>(lq1, lk1, lq2, lk2, lamv);

  dim3 gg(1024 / 128, 4096 / 128);  // (8, 32)
  gemm128<<<gg, 256, 0, stream>>>(xq,  WqT, qb,  nullptr, 4096, 1024, 1024);
  gemm128<<<gg, 256, 0, stream>>>(xkv, WkT, kbf, nullptr, 4096, 1024, 1024);
  gemm128<<<gg, 256, 0, stream>>>(xkv, WvT, vbf, nullptr, 4096, 1024, 1024);

  diffattn<<<1024, 256, 0, stream>>>(qb, kbf, vbf, lamv, subw, a16);

  gemm128<<<gg, 256, 0, stream>>>(a16, WoT, nullptr, out, 4096, 1024, 1024);
}

// Round 3
// 324.770 us; speedup vs baseline: 1.1475x; 1.1475x over previous
//
#include <hip/hip_runtime.h>
#include <stdint.h>

// ---------------------------------------------------------------------------
// CrossMultiheadDiffAttn on MI355X (gfx950)
// B=2, T=S=2048, EMBED=1024, HEADS=16; 2H=32 qk-heads of D=32, 16 v-heads of 64.
//
// Round 3: register-resident diff-attention (swapped-operand 32x32 MFMA,
// per-lane softmax state, no LDS, defer-max, exp2 domain). V^T produced
// directly by operand-swapped projection GEMM. (R2 + cvt_pkrtz type fix.)
// ---------------------------------------------------------------------------

#define LAMBDA_INIT_F 0.7836057665316245f
#define OUT_SCALE_F   0.2163942334683755f   /* 1 - LAMBDA_INIT */
#define QK_SCALE_F    0.17677669529663687f  /* 32^-0.5 */
#define LOG2E_F       1.4426950408889634f

typedef _Float16 f16x8 __attribute__((ext_vector_type(8)));
typedef _Float16 f16x4 __attribute__((ext_vector_type(4)));
typedef _Float16 f16x2 __attribute__((ext_vector_type(2)));
typedef __fp16   h16x2 __attribute__((ext_vector_type(2)));
typedef float    f32x4 __attribute__((ext_vector_type(4)));
typedef float    f32x16 __attribute__((ext_vector_type(16)));

__device__ inline void gl_lds16(const void* g, void* l) {
  __builtin_amdgcn_global_load_lds(
      (const __attribute__((address_space(1))) void*)g,
      (__attribute__((address_space(3))) void*)l, 16, 0, 0);
}

__device__ inline f16x2 shx32(f16x2 v) {
  int i = __builtin_bit_cast(int, v);
  i = __shfl_xor(i, 32, 64);
  return __builtin_bit_cast(f16x2, i);
}

__device__ inline f16x2 cvtpk(float a, float b) {
  h16x2 r = __builtin_amdgcn_cvt_pkrtz(a, b);
  return __builtin_bit_cast(f16x2, r);
}

// --------------------------- f32 -> f16 convert ----------------------------
__global__ __launch_bounds__(256) void cvt_kernel(const float* __restrict__ x,
                                                  _Float16* __restrict__ y) {
  int i = (blockIdx.x * 256 + threadIdx.x) * 4;
  float4 v = *(const float4*)(x + i);
  f16x4 o;
  o[0] = (_Float16)v.x; o[1] = (_Float16)v.y;
  o[2] = (_Float16)v.z; o[3] = (_Float16)v.w;
  *(f16x4*)(y + i) = o;
}

// ---------------- W [K,N] f32 -> W^T [N,K] f16 (with scale) ----------------
__global__ __launch_bounds__(256) void wtrans_kernel(const float* __restrict__ W,
                                                     _Float16* __restrict__ Wt,
                                                     float scale) {
  __shared__ _Float16 t[64][65];
  const int tid = threadIdx.x;
  const int nb = blockIdx.x * 64, kb = blockIdx.y * 64;
#pragma unroll
  for (int p = 0; p < 16; ++p) {
    int i = p * 256 + tid;
    int r = i >> 6, c = i & 63;
    t[c][r] = (_Float16)(W[(size_t)(kb + r) * 1024 + nb + c] * scale);
  }
  __syncthreads();
#pragma unroll
  for (int p = 0; p < 16; ++p) {
    int i = p * 256 + tid;
    int r = i >> 6, c = i & 63;
    Wt[(size_t)(nb + r) * 1024 + kb + c] = t[r][c];
  }
}

// ------------------------------ lambda_full --------------------------------
__global__ void lambda_kernel(const float* __restrict__ lq1, const float* __restrict__ lk1,
                              const float* __restrict__ lq2, const float* __restrict__ lk2,
                              float* __restrict__ out) {
  int l = threadIdx.x;
  float a = (l < 32) ? lq1[l] * lk1[l] : 0.f;
  float b = (l < 32) ? lq2[l] * lk2[l] : 0.f;
#pragma unroll
  for (int m = 1; m < 64; m <<= 1) {
    a += __shfl_xor(a, m, 64);
    b += __shfl_xor(b, m, 64);
  }
  if (l == 0) out[0] = expf(a) - expf(b) + LAMBDA_INIT_F;
}

// --------------------- 128x128 f16 GEMM:  C = A @ Bt^T ---------------------
__global__ __launch_bounds__(256) void gemm128(const _Float16* __restrict__ A,
                                               const _Float16* __restrict__ Bt,
                                               _Float16* __restrict__ Cf16,
                                               float* __restrict__ Cf32,
                                               int M, int N, int K) {
  __shared__ alignas(16) _Float16 As[128 * 32];
  __shared__ alignas(16) _Float16 Bs[128 * 32];
  const int tid = threadIdx.x;
  const int lane = tid & 63, wid = tid >> 6;
  const int g = lane >> 4, ln = lane & 15;
  const int wm = wid >> 1, wn = wid & 1;
  const int bm = blockIdx.y * 128;
  const int bn = blockIdx.x * 128;

  f32x4 acc[4][4];
#pragma unroll
  for (int i = 0; i < 4; ++i)
#pragma unroll
    for (int j = 0; j < 4; ++j) acc[i][j] = (f32x4){0.f, 0.f, 0.f, 0.f};

  const int r0 = tid >> 2;
  const int c0 = (tid & 3) * 8;

  for (int kt = 0; kt < K; kt += 32) {
    __syncthreads();
#pragma unroll
    for (int l = 0; l < 2; ++l) {
      const _Float16* ga = A + (size_t)(bm + l * 64 + r0) * K + kt + c0;
      const _Float16* gb = Bt + (size_t)(bn + l * 64 + r0) * K + kt + c0;
      gl_lds16(ga, (void*)(As + l * 2048 + wid * 512));
      gl_lds16(gb, (void*)(Bs + l * 2048 + wid * 512));
    }
    __syncthreads();
    f16x8 af[4], bf[4];
#pragma unroll
    for (int i = 0; i < 4; ++i) {
      af[i] = *(const f16x8*)(As + (wm * 64 + i * 16 + ln) * 32 + g * 8);
      bf[i] = *(const f16x8*)(Bs + (wn * 64 + i * 16 + ln) * 32 + g * 8);
    }
#pragma unroll
    for (int i = 0; i < 4; ++i)
#pragma unroll
      for (int j = 0; j < 4; ++j)
        acc[i][j] = __builtin_amdgcn_mfma_f32_16x16x32_f16(af[i], bf[j], acc[i][j], 0, 0, 0);
  }

#pragma unroll
  for (int i = 0; i < 4; ++i) {
#pragma unroll
    for (int j = 0; j < 4; ++j) {
      int grow = bm + wm * 64 + i * 16 + g * 4;
      int gcol = bn + wn * 64 + j * 16 + ln;
#pragma unroll
      for (int r = 0; r < 4; ++r) {
        if (Cf32) Cf32[(size_t)(grow + r) * N + gcol] = acc[i][j][r];
        else      Cf16[(size_t)(grow + r) * N + gcol] = (_Float16)acc[i][j][r];
      }
    }
  }
}

// ------------------- register-resident differential attention --------------
// grid = 512 blocks (b,h,qtile of 128), 4 waves x 32 q-rows. No LDS.
// Scores computed in exp2 domain (Wq pre-scaled by QK_SCALE*log2e).
// S^T = K . Q^T  (32x32x16 mfma x2): lane owns q = lane&31; per-q state scalar.
// O^T = V^T . P^T: same col=q layout; V^T rows contiguous (vT buffer).
__global__ __launch_bounds__(256) void diffattn(const _Float16* __restrict__ qb,
                                                const _Float16* __restrict__ kb,
                                                const _Float16* __restrict__ vT,
                                                const float* __restrict__ lam_p,
                                                const float* __restrict__ subw,
                                                _Float16* __restrict__ attn16) {
  const int tid = threadIdx.x;
  const int lane = tid & 63, wid = tid >> 6;
  const int q32 = lane & 31;
  const int hl = lane >> 5;
  const int bid = blockIdx.x;
  const int qt = bid & 15;
  const int h = (bid >> 4) & 15;
  const int b = bid >> 8;
  const int trow = qt * 128 + wid * 32 + q32;
  const float lam = lam_p[0];

  // Q B-fragments: lane holds Q[q=lane&31][d = 16*kt + 8*hl + i]
  const _Float16* qp = qb + ((size_t)b * 2048 + trow) * 1024 + 2 * h * 32 + hl * 8;
  f16x8 qf1_0 = *(const f16x8*)(qp);
  f16x8 qf1_1 = *(const f16x8*)(qp + 16);
  f16x8 qf2_0 = *(const f16x8*)(qp + 32);
  f16x8 qf2_1 = *(const f16x8*)(qp + 48);

  const _Float16* kbase = kb + (size_t)b * 2048 * 1024 + 2 * h * 32 + hl * 8;
  const _Float16* vbase = vT + ((size_t)(h * 64 + q32)) * 4096 + b * 2048 + hl * 8;

  f32x16 O1[2] = {}, O2[2] = {};
  float m1 = -1e30f, m2 = -1e30f, l1 = 0.f, l2 = 0.f;
  const f32x16 zf = {};

  auto LOADT = [&](f16x8* K4, f16x8* V4, int s0) {
    const _Float16* kp = kbase + (size_t)(s0 + q32) * 1024;
    K4[0] = *(const f16x8*)(kp);
    K4[1] = *(const f16x8*)(kp + 16);
    K4[2] = *(const f16x8*)(kp + 32);
    K4[3] = *(const f16x8*)(kp + 48);
    const _Float16* vp = vbase + s0;
    V4[0] = *(const f16x8*)(vp);
    V4[1] = *(const f16x8*)(vp + 16);
    V4[2] = *(const f16x8*)(vp + 32 * 4096);
    V4[3] = *(const f16x8*)(vp + 32 * 4096 + 16);
  };

  // softmax+pack one component: st (exp2-domain scores), returns PV B-frags
  // via cvt_pkrtz + cross-half shuffle (T12).
  auto SOFTPACK = [&](const f32x16& st, float m, float& lsum, f16x8& pb0, f16x8& pb1) {
    float p[16];
    float rs = 0.f;
#pragma unroll
    for (int i = 0; i < 16; ++i) {
      p[i] = __builtin_amdgcn_exp2f(st[i] - m);
      rs += p[i];
    }
    lsum += rs + __shfl_xor(rs, 32, 64);
    f16x2 r[8], xr[8];
#pragma unroll
    for (int k = 0; k < 8; ++k) r[k] = cvtpk(p[2 * k], p[2 * k + 1]);
#pragma unroll
    for (int k = 0; k < 8; ++k) xr[k] = shx32(r[k]);
    union { f16x8 v; f16x2 h2[4]; } u0, u1;
    u0.h2[0] = hl ? xr[2] : r[0];
    u0.h2[1] = hl ? xr[3] : r[1];
    u0.h2[2] = hl ? r[2]  : xr[0];
    u0.h2[3] = hl ? r[3]  : xr[1];
    u1.h2[0] = hl ? xr[6] : r[4];
    u1.h2[1] = hl ? xr[7] : r[5];
    u1.h2[2] = hl ? r[6]  : xr[4];
    u1.h2[3] = hl ? r[7]  : xr[5];
    pb0 = u0.v; pb1 = u1.v;
  };

  auto PROC = [&](const f16x8* K4, const f16x8* V4) {
    f32x16 st1 = __builtin_amdgcn_mfma_f32_32x32x16_f16(K4[0], qf1_0, zf, 0, 0, 0);
    f32x16 st2 = __builtin_amdgcn_mfma_f32_32x32x16_f16(K4[2], qf2_0, zf, 0, 0, 0);
    st1 = __builtin_amdgcn_mfma_f32_32x32x16_f16(K4[1], qf1_1, st1, 0, 0, 0);
    st2 = __builtin_amdgcn_mfma_f32_32x32x16_f16(K4[3], qf2_1, st2, 0, 0, 0);

    float tm1 = st1[0], tm2 = st2[0];
#pragma unroll
    for (int i = 1; i < 16; ++i) {
      tm1 = fmaxf(tm1, st1[i]);
      tm2 = fmaxf(tm2, st2[i]);
    }
    tm1 = fmaxf(tm1, __shfl_xor(tm1, 32, 64));
    tm2 = fmaxf(tm2, __shfl_xor(tm2, 32, 64));

    // defer-max (T13): only rescale when a tile max exceeds running max + THR
    if (!__all(fmaxf(tm1 - m1, tm2 - m2) <= 11.5f)) {
      float mn1 = fmaxf(m1, tm1), mn2 = fmaxf(m2, tm2);
      float c1 = __builtin_amdgcn_exp2f(m1 - mn1);
      float c2 = __builtin_amdgcn_exp2f(m2 - mn2);
      m1 = mn1; m2 = mn2; l1 *= c1; l2 *= c2;
#pragma unroll
      for (int i = 0; i < 16; ++i) {
        O1[0][i] *= c1; O1[1][i] *= c1;
        O2[0][i] *= c2; O2[1][i] *= c2;
      }
    }

    f16x8 p1b0, p1b1, p2b0, p2b1;
    SOFTPACK(st1, m1, l1, p1b0, p1b1);
    SOFTPACK(st2, m2, l2, p2b0, p2b1);

    O1[0] = __builtin_amdgcn_mfma_f32_32x32x16_f16(V4[0], p1b0, O1[0], 0, 0, 0);
    O1[0] = __builtin_amdgcn_mfma_f32_32x32x16_f16(V4[1], p1b1, O1[0], 0, 0, 0);
    O1[1] = __builtin_amdgcn_mfma_f32_32x32x16_f16(V4[2], p1b0, O1[1], 0, 0, 0);
    O1[1] = __builtin_amdgcn_mfma_f32_32x32x16_f16(V4[3], p1b1, O1[1], 0, 0, 0);
    O2[0] = __builtin_amdgcn_mfma_f32_32x32x16_f16(V4[0], p2b0, O2[0], 0, 0, 0);
    O2[0] = __builtin_amdgcn_mfma_f32_32x32x16_f16(V4[1], p2b1, O2[0], 0, 0, 0);
    O2[1] = __builtin_amdgcn_mfma_f32_32x32x16_f16(V4[2], p2b0, O2[1], 0, 0, 0);
    O2[1] = __builtin_amdgcn_mfma_f32_32x32x16_f16(V4[3], p2b1, O2[1], 0, 0, 0);
  };

  f16x8 Ka[4], Va[4], Kb[4], Vb[4];
  LOADT(Ka, Va, 0);
  for (int s0 = 0; s0 < 2048; s0 += 64) {
    LOADT(Kb, Vb, s0 + 32);
    PROC(Ka, Va);
    if (s0 + 64 < 2048) LOADT(Ka, Va, s0 + 64);
    PROC(Kb, Vb);
  }

  // epilogue: diff, RMSNorm over 64 dims (local 32 + partner via 1 shuffle)
  float rl1 = 1.f / l1;
  float rl2 = lam / l2;
  float x[2][16];
  float ssq = 0.f;
#pragma unroll
  for (int et = 0; et < 2; ++et)
#pragma unroll
    for (int i = 0; i < 16; ++i) {
      float v = O1[et][i] * rl1 - O2[et][i] * rl2;
      x[et][i] = v;
      ssq += v * v;
    }
  ssq += __shfl_xor(ssq, 32, 64);
  float rms = rsqrtf(ssq * (1.f / 64.f) + 1e-5f) * OUT_SCALE_F;

  _Float16* orow = attn16 + ((size_t)b * 2048 + trow) * 1024 + h * 64;
#pragma unroll
  for (int et = 0; et < 2; ++et)
#pragma unroll
    for (int grp = 0; grp < 4; ++grp) {
      int e0 = et * 32 + grp * 8 + 4 * hl;
      float4 w = *(const float4*)(subw + e0);
      f16x4 o;
      o[0] = (_Float16)(x[et][grp * 4 + 0] * rms * w.x);
      o[1] = (_Float16)(x[et][grp * 4 + 1] * rms * w.y);
      o[2] = (_Float16)(x[et][grp * 4 + 2] * rms * w.z);
      o[3] = (_Float16)(x[et][grp * 4 + 3] * rms * w.w);
      *(f16x4*)(orow + e0) = o;
    }
}

// ---------------------------------------------------------------------------
extern "C" void kernel_launch(void* const* d_in, const int* in_sizes, int n_in,
                              void* d_out, int out_size, void* d_ws, size_t ws_size,
                              hipStream_t stream) {
  const float* query_x = (const float*)d_in[0];
  const float* kv_x    = (const float*)d_in[1];
  const float* Wq      = (const float*)d_in[2];
  const float* Wk      = (const float*)d_in[3];
  const float* Wv      = (const float*)d_in[4];
  const float* Wo      = (const float*)d_in[5];
  const float* lq1     = (const float*)d_in[6];
  const float* lk1     = (const float*)d_in[7];
  const float* lq2     = (const float*)d_in[8];
  const float* lk2     = (const float*)d_in[9];
  const float* subw    = (const float*)d_in[10];
  float* out = (float*)d_out;

  const size_t NX = (size_t)4096 * 1024;
  const size_t NW = (size_t)1024 * 1024;
  _Float16* xq  = (_Float16*)d_ws;
  _Float16* xkv = xq  + NX;
  _Float16* WqT = xkv + NX;
  _Float16* WkT = WqT + NW;
  _Float16* WvT = WkT + NW;
  _Float16* WoT = WvT + NW;
  _Float16* qb  = WoT + NW;
  _Float16* kbf = qb  + NX;
  _Float16* vTb = kbf + NX;   // V^T: [1024 rows = h*64+e][4096 cols = b*2048+s]
  _Float16* a16 = vTb + NX;
  float* lamv   = (float*)(a16 + NX);

  cvt_kernel<<<4096, 256, 0, stream>>>(query_x, xq);
  cvt_kernel<<<4096, 256, 0, stream>>>(kv_x, xkv);

  dim3 tg(16, 16);
  // Wq also folds log2e so attention scores are directly in exp2 domain
  wtrans_kernel<<<tg, 256, 0, stream>>>(Wq, WqT, QK_SCALE_F * LOG2E_F);
  wtrans_kernel<<<tg, 256, 0, stream>>>(Wk, WkT, 1.0f);
  wtrans_kernel<<<tg, 256, 0, stream>>>(Wv, WvT, 1.0f);
  wtrans_kernel<<<tg, 256, 0, stream>>>(Wo, WoT, 1.0f);
  lambda_kernel<<<1, 64, 0, stream>>>(lq1, lk1, lq2, lk2, lamv);

  dim3 gg(8, 32);   // (N/128, M/128) for 4096x1024
  gemm128<<<gg, 256, 0, stream>>>(xq,  WqT, qb,  nullptr, 4096, 1024, 1024);
  gemm128<<<gg, 256, 0, stream>>>(xkv, WkT, kbf, nullptr, 4096, 1024, 1024);
  // V^T directly: C[n][m] = sum_k WvT[n][k]*xkv[m][k] = V[m][n]
  dim3 gv(32, 8);   // (N/128=4096/128, M/128=1024/128)
  gemm128<<<gv, 256, 0, stream>>>(WvT, xkv, vTb, nullptr, 1024, 4096, 1024);

  diffattn<<<512, 256, 0, stream>>>(qb, kbf, vTb, lamv, subw, a16);

  gemm128<<<gg, 256, 0, stream>>>(a16, WoT, nullptr, out, 4096, 1024, 1024);
}